// Round 6
// baseline (60.128 us; speedup 1.0000x reference)
//
#include <hip/hip_runtime.h>

#define B_ 8
#define C_ 64
#define H_ 192
#define W_ 320
#define HW_ (H_*W_)
#define OUT_ELEMS ((size_t)B_*C_*H_*W_)

#define CSPLIT 4            // channel chunks per batch
#define CPB    (C_/CSPLIT)  // 16 channels per block
#define NTHR   320          // 5 waves; t%80 = pixel-group, t/80 = channel group

typedef float f32x4 __attribute__((ext_vector_type(4)));

// Per-batch parameter block stored in d_ws as doubles:
// [m00, m01, m02, m10, m12, m20, m22, s, cx] (m11=m21=0 omitted)
__global__ void bev_setup_kernel(const float* __restrict__ h_cam,
                                 const float* __restrict__ p_cam,
                                 const float* __restrict__ fu,
                                 const float* __restrict__ fv,
                                 const int*   __restrict__ plane_h,
                                 double* __restrict__ params,
                                 float*  __restrict__ scales_out,
                                 float*  __restrict__ centers_out) {
    int b = threadIdx.x;
    if (b >= B_) return;
    const double D  = 1e-16;
    const double cu = W_ / 2.0;   // 160
    const double cv = H_ / 2.0;   // 96
    double h   = (double)h_cam[b];
    double p   = (double)p_cam[b];
    double dfu = (double)fu[b];
    double dfv = (double)fv[b];
    double ph  = (double)plane_h[0];
    double h_ref = h - ph;
    double sp = sin(p), cp = cos(p);

    double m00 = cu * cp;
    double m01 = -dfu;
    double m02 = cu * h_ref * sp;
    double m10 = cv * cp - dfv * sp;
    double m12 = h_ref * (dfv * cp + cv * sp);
    double m20 = cp;
    double m22 = h_ref * sp;
    double s   = h / (sp * (cv * cp + dfv * sp) + D);
    double cx  = h * cp / (sp + D);

    double* pp = params + (size_t)b * 10;
    pp[0] = m00; pp[1] = m01; pp[2] = m02;
    pp[3] = m10; pp[4] = m12;
    pp[5] = m20; pp[6] = m22;
    pp[7] = s;   pp[8] = cx;

    scales_out[b] = (float)s;
    centers_out[b*3 + 0] = (float)cx;
    centers_out[b*3 + 1] = 0.0f;
    centers_out[b*3 + 2] = 1.0f;
}

__global__ __launch_bounds__(NTHR)
void bev_row_kernel(const float* __restrict__ x,
                    const double* __restrict__ params,
                    float* __restrict__ out) {
    const int v  = blockIdx.x;                 // output row
    const int b  = blockIdx.y >> 2;            // CSPLIT = 4
    const int c0 = (blockIdx.y & 3) * CPB;
    const int t  = threadIdx.x;

    const double* pp = params + (size_t)b * 10;
    const double m00 = pp[0], m01 = pp[1], m02 = pp[2];
    const double m10 = pp[3], m12 = pp[4];
    const double m20 = pp[5], m22 = pp[6];
    const double s   = pp[7], cx  = pp[8];

    // Row-level geometry: sv/t2 constant over the row; su affine in u.
    const double wx     = cx + s * ((double)(H_/2) - (double)v);
    const double t2     = m20 * wx + m22;
    const double inv_t2 = 1.0 / t2;
    const double sv     = (m10 * wx + m12) * inv_t2;
    const double su_c   = (m00 * wx + m02) * inv_t2;
    const double su_k   = m01 * s * inv_t2;

    const bool rowin = (sv >= 0.0) && (sv < (double)(H_-1));
    int v0i = 0;
    float dv0 = 0.f, dv1 = 0.f;
    if (rowin) {
        v0i = (int)sv;
        dv0 = (float)(sv - (double)v0i);
        dv1 = (float)((double)(v0i + 1) - sv);
    }

    // Two input rows x 16 channels staged in LDS, coalesced float4 loads.
    __shared__ __align__(16) float rows[2][CPB][W_];   // 40 KB
    if (rowin) {
        const float* __restrict__ src =
            x + (((size_t)(b * C_ + c0)) * H_ + (size_t)v0i) * W_;
        #pragma unroll
        for (int j = 0; j < (2 * CPB * (W_/4)) / NTHR; ++j) {   // 2560/320 = 8
            const int i   = t + j * NTHR;
            const int c   = i / 160;           // channel
            const int rem = i - c * 160;
            const int rr  = rem / 80;          // row 0/1
            const int q   = rem - rr * 80;     // float4 index in row
            const f32x4 val = *(const f32x4*)(src + ((size_t)c * H_ + (size_t)rr) * W_ + (size_t)q * 4);
            *(f32x4*)&rows[rr][c][q * 4] = val;
        }
    }
    __syncthreads();

    const int p4  = t % 80;      // pixel group (4 consecutive u)
    const int chg = t / 80;      // 0..3 -> 4 channels each
    const int u0  = p4 * 4;

    float wA[4], wB[4], wC[4], wD[4];
    int col[4];
    #pragma unroll
    for (int k = 0; k < 4; ++k) {
        const double su = su_c + su_k * ((double)(W_/2) - (double)(u0 + k));
        const bool inr = rowin && (su >= 0.0) && (su < (double)(W_-1));
        int ui = 0;
        float du0 = 0.f, du1 = 0.f;
        if (inr) {
            ui  = (int)su;
            du0 = (float)(su - (double)ui);
            du1 = (float)((double)(ui + 1) - su);
        }
        wA[k] = dv1 * du1;   // (v0, u0)
        wB[k] = dv0 * du1;   // (v1, u0)
        wC[k] = dv1 * du0;   // (v0, u1)
        wD[k] = dv0 * du0;   // (v1, u1)
        col[k] = ui;
    }

    float* __restrict__ ob =
        out + (((size_t)(b * C_ + c0 + chg * 4)) * H_ + (size_t)v) * W_ + (size_t)u0;

    #pragma unroll
    for (int cc = 0; cc < 4; ++cc) {
        const float* __restrict__ r0 = rows[0][chg * 4 + cc];
        const float* __restrict__ r1 = rows[1][chg * 4 + cc];
        f32x4 r;
        r.x = wA[0]*r0[col[0]] + wC[0]*r0[col[0]+1] + wB[0]*r1[col[0]] + wD[0]*r1[col[0]+1];
        r.y = wA[1]*r0[col[1]] + wC[1]*r0[col[1]+1] + wB[1]*r1[col[1]] + wD[1]*r1[col[1]+1];
        r.z = wA[2]*r0[col[2]] + wC[2]*r0[col[2]+1] + wB[2]*r1[col[2]] + wD[2]*r1[col[2]+1];
        r.w = wA[3]*r0[col[3]] + wC[3]*r0[col[3]+1] + wB[3]*r1[col[3]] + wD[3]*r1[col[3]+1];
        __builtin_nontemporal_store(r, (f32x4*)(ob + (size_t)cc * HW_));
    }
}

extern "C" void kernel_launch(void* const* d_in, const int* in_sizes, int n_in,
                              void* d_out, int out_size, void* d_ws, size_t ws_size,
                              hipStream_t stream) {
    const float* x     = (const float*)d_in[0];
    const float* h_cam = (const float*)d_in[1];
    const float* p_cam = (const float*)d_in[2];
    const float* fu    = (const float*)d_in[3];
    const float* fv    = (const float*)d_in[4];
    const int*   ph    = (const int*)  d_in[5];

    float* out = (float*)d_out;
    float* scales_out  = out + OUT_ELEMS;        // 8 floats
    float* centers_out = out + OUT_ELEMS + B_;   // 24 floats
    double* params = (double*)d_ws;              // 8 * 10 doubles = 640 B

    bev_setup_kernel<<<1, 64, 0, stream>>>(h_cam, p_cam, fu, fv, ph,
                                           params, scales_out, centers_out);

    dim3 grid(H_, B_ * CSPLIT);   // 192 x 32 = 6144 blocks, 5 waves each
    bev_row_kernel<<<grid, NTHR, 0, stream>>>(x, params, out);
}

// Round 7
// 44.535 us; speedup vs baseline: 1.3501x; 1.3501x over previous
//
#include <hip/hip_runtime.h>

#define B_ 8
#define C_ 64
#define H_ 192
#define W_ 320
#define HW_ (H_*W_)
#define OUT_ELEMS ((size_t)B_*C_*H_*W_)

#define CSPLIT 8            // channel chunks per batch
#define CPB    (C_/CSPLIT)  // 8 channels per block
#define CGRP   4            // channels per load-group
#define PIXT   4            // pixels per thread (float4 store)
#define XTILES (HW_/(256*PIXT))   // 60 pixel-tiles per (b,chunk)
#define NWG    (XTILES * B_ * CSPLIT)  // 3840
#define NXCD   8

typedef float f32x4 __attribute__((ext_vector_type(4)));

// 8-byte tap-pair with only 4-byte alignment guarantee -> global_load_dwordx2.
struct __attribute__((packed, aligned(4))) fpair { float lo, hi; };

// Per-batch parameter block stored in d_ws as doubles:
// [m00, m01, m02, m10, m12, m20, m22, s, cx] (m11=m21=0 omitted)
__global__ void bev_setup_kernel(const float* __restrict__ h_cam,
                                 const float* __restrict__ p_cam,
                                 const float* __restrict__ fu,
                                 const float* __restrict__ fv,
                                 const int*   __restrict__ plane_h,
                                 double* __restrict__ params,
                                 float*  __restrict__ scales_out,
                                 float*  __restrict__ centers_out) {
    int b = threadIdx.x;
    if (b >= B_) return;
    const double D  = 1e-16;
    const double cu = W_ / 2.0;   // 160
    const double cv = H_ / 2.0;   // 96
    double h   = (double)h_cam[b];
    double p   = (double)p_cam[b];
    double dfu = (double)fu[b];
    double dfv = (double)fv[b];
    double ph  = (double)plane_h[0];
    double h_ref = h - ph;
    double sp = sin(p), cp = cos(p);

    double m00 = cu * cp;
    double m01 = -dfu;
    double m02 = cu * h_ref * sp;
    double m10 = cv * cp - dfv * sp;
    double m12 = h_ref * (dfv * cp + cv * sp);
    double m20 = cp;
    double m22 = h_ref * sp;
    double s   = h / (sp * (cv * cp + dfv * sp) + D);
    double cx  = h * cp / (sp + D);

    double* pp = params + (size_t)b * 10;
    pp[0] = m00; pp[1] = m01; pp[2] = m02;
    pp[3] = m10; pp[4] = m12;
    pp[5] = m20; pp[6] = m22;
    pp[7] = s;   pp[8] = cx;

    scales_out[b] = (float)s;
    centers_out[b*3 + 0] = (float)cx;
    centers_out[b*3 + 1] = 0.0f;
    centers_out[b*3 + 2] = 1.0f;
}

__global__ __launch_bounds__(256, 4)
void bev_main_kernel(const float* __restrict__ x,
                     const double* __restrict__ params,
                     float* __restrict__ out) {
    // XCD-aware bijective swizzle (T1): XCD k (= wg % 8 dispatch round-robin)
    // gets the contiguous chunk [k*480, (k+1)*480) of logical block ids.
    // Logical order: bc-major, x-tile minor -> each XCD streams one batch's
    // channel-chunks (1.9 MB each) through its private L2.
    const int wg    = blockIdx.x;                      // 0..NWG-1
    const int newid = (wg % NXCD) * (NWG / NXCD) + (wg / NXCD);
    const int bc    = newid / XTILES;                  // 0..63
    const int xt    = newid - bc * XTILES;             // 0..59
    const int b     = bc >> 3;                         // CSPLIT = 8
    const int c0    = (bc & 7) * CPB;
    const int pix0  = (xt * 256 + threadIdx.x) * PIXT;
    const int v     = pix0 / W_;                       // 4 | W: all 4 px same row
    const int u     = pix0 - v * W_;

    const double* pp = params + (size_t)b * 10;
    const double m00 = pp[0], m01 = pp[1], m02 = pp[2];
    const double m10 = pp[3], m12 = pp[4];
    const double m20 = pp[5], m22 = pp[6];
    const double s   = pp[7], cx  = pp[8];

    // Row-level geometry: t2 and sv depend only on v; su is affine in u.
    const double wx     = cx + s * ((double)(H_/2) - (double)v);
    const double t2     = m20 * wx + m22;
    const double inv_t2 = 1.0 / t2;
    const double sv     = (m10 * wx + m12) * inv_t2;
    const double su_c   = (m00 * wx + m02) * inv_t2;   // constant part
    const double su_k   = m01 * s * inv_t2;            // coeff of (cu - u)

    const bool rowin = (sv >= 0.0) && (sv < (double)(H_-1));
    int v0i = 0;
    float dv0 = 0.f, dv1 = 0.f;
    if (rowin) {
        v0i = (int)sv;                          // sv >= 0
        dv0 = (float)(sv - (double)v0i);
        dv1 = (float)((double)(v0i + 1) - sv);
    }

    float wa[PIXT], wb[PIXT], wc[PIXT], wd[PIXT];
    int   base[PIXT];
    #pragma unroll
    for (int k = 0; k < PIXT; ++k) {
        const double su = su_c + su_k * ((double)(W_/2) - (double)(u + k));
        const bool inr = rowin && (su >= 0.0) && (su < (double)(W_-1));
        int u0i = 0;
        float du0 = 0.f, du1 = 0.f;
        if (inr) {
            u0i = (int)su;
            du0 = (float)(su - (double)u0i);
            du1 = (float)((double)(u0i + 1) - su);
        }
        wa[k] = dv1 * du1;   // (v0, u0)
        wb[k] = dv0 * du1;   // (v1, u0)
        wc[k] = dv1 * du0;   // (v0, u1)
        wd[k] = dv0 * du0;   // (v1, u1)
        base[k] = v0i * W_ + u0i;
    }

    const float* __restrict__ xb = x   + ((size_t)(b * C_ + c0)) * HW_;
    float* __restrict__       ob = out + ((size_t)(b * C_ + c0)) * HW_ + (size_t)pix0;

    // Each pixel's 4 taps = 2 horizontally-adjacent pairs -> 2 dwordx2 gathers.
    #pragma unroll
    for (int g = 0; g < CPB / CGRP; ++g) {
        fpair tp[CGRP][PIXT], bp[CGRP][PIXT];
        #pragma unroll
        for (int c = 0; c < CGRP; ++c) {
            const float* __restrict__ xc = xb + (size_t)(g * CGRP + c) * HW_;
            #pragma unroll
            for (int k = 0; k < PIXT; ++k) {
                tp[c][k] = *(const fpair*)(xc + base[k]);        // (v0,u0),(v0,u1)
                bp[c][k] = *(const fpair*)(xc + base[k] + W_);   // (v1,u0),(v1,u1)
            }
        }
        #pragma unroll
        for (int c = 0; c < CGRP; ++c) {
            f32x4 r;
            r.x = wa[0]*tp[c][0].lo + wc[0]*tp[c][0].hi + wb[0]*bp[c][0].lo + wd[0]*bp[c][0].hi;
            r.y = wa[1]*tp[c][1].lo + wc[1]*tp[c][1].hi + wb[1]*bp[c][1].lo + wd[1]*bp[c][1].hi;
            r.z = wa[2]*tp[c][2].lo + wc[2]*tp[c][2].hi + wb[2]*bp[c][2].lo + wd[2]*bp[c][2].hi;
            r.w = wa[3]*tp[c][3].lo + wc[3]*tp[c][3].hi + wb[3]*bp[c][3].lo + wd[3]*bp[c][3].hi;
            __builtin_nontemporal_store(r, (f32x4*)(ob + (size_t)(g * CGRP + c) * HW_));
        }
    }
}

extern "C" void kernel_launch(void* const* d_in, const int* in_sizes, int n_in,
                              void* d_out, int out_size, void* d_ws, size_t ws_size,
                              hipStream_t stream) {
    const float* x     = (const float*)d_in[0];
    const float* h_cam = (const float*)d_in[1];
    const float* p_cam = (const float*)d_in[2];
    const float* fu    = (const float*)d_in[3];
    const float* fv    = (const float*)d_in[4];
    const int*   ph    = (const int*)  d_in[5];

    float* out = (float*)d_out;
    float* scales_out  = out + OUT_ELEMS;        // 8 floats
    float* centers_out = out + OUT_ELEMS + B_;   // 24 floats
    double* params = (double*)d_ws;              // 8 * 10 doubles = 640 B

    bev_setup_kernel<<<1, 64, 0, stream>>>(h_cam, p_cam, fu, fv, ph,
                                           params, scales_out, centers_out);

    bev_main_kernel<<<NWG, 256, 0, stream>>>(x, params, out);
}